// Round 6
// baseline (464.779 us; speedup 1.0000x reference)
//
#include <hip/hip_runtime.h>
#include <hip/hip_bf16.h>
#include <math.h>

// Problem constants (B=4, S=2048, Hd=1024, h=16, d=64). fp32 in/out per the
// reference; bf16 internally (MFMA) with fp32 accumulation.
#define B_SZ   4
#define S_LEN  2048
#define HD     1024
#define NHEAD  16
#define DHEAD  64
#define N3     3072          // 3*Hd
#define M_ROWS 8192          // B*S

typedef __bf16 bf16_t;
typedef __bf16 bf16x4 __attribute__((ext_vector_type(4)));
typedef __bf16 bf16x8 __attribute__((ext_vector_type(8)));
typedef float  floatx4 __attribute__((ext_vector_type(4)));

__device__ __forceinline__ float bf2f(bf16_t x) { return (float)x; }
__device__ __forceinline__ bf16_t f2bf(float f) { return (bf16_t)f; }  // RNE fptrunc

__device__ __forceinline__ bf16x8 cvt8(const float4 lo, const float4 hi) {
    bf16x8 r;
    r[0] = (bf16_t)lo.x; r[1] = (bf16_t)lo.y; r[2] = (bf16_t)lo.z; r[3] = (bf16_t)lo.w;
    r[4] = (bf16_t)hi.x; r[5] = (bf16_t)hi.y; r[6] = (bf16_t)hi.z; r[7] = (bf16_t)hi.w;
    return r;
}

// ---------------------------------------------------------------------------
// Kernel 1 (round-3 version, measured ~163 us): qkv = X @ W^T + b, fused RoPE
// on q,k; scatter bf16 [b][h][s][d]. v's [s][d] copy goes into d_out (bf16 in
// the fp32 out buffer — fully overwritten by attn later; stream-ordered).
// [d][s] direct scatter from here is banned (round-4: 3 GB write amp).
// ---------------------------------------------------------------------------
__global__ __launch_bounds__(256, 3)
void qkv_rope_kernel(const float* __restrict__ X, const float* __restrict__ W,
                     const float* __restrict__ bias,
                     bf16_t* __restrict__ qws, bf16_t* __restrict__ kws,
                     bf16_t* __restrict__ vws)
{
    __shared__ bf16_t As[128 * 32];   // 8 KB, [row][32] bf16 (16-dword rows)
    __shared__ bf16_t Bs[128 * 32];   // 8 KB

    const int tid  = threadIdx.x;
    const int wave = tid >> 6;
    const int lane = tid & 63;
    const int l15  = lane & 15;
    const int quad = lane >> 4;
    const int wm   = wave >> 1;
    const int wn   = wave & 1;
    const int m0   = blockIdx.y * 128;
    const int n0   = blockIdx.x * 128;

    const int b0   = tid;
    const int b1   = tid + 256;
    const int r0   = b0 >> 2, c0 = (b0 & 3) * 8;
    const int r1   = b1 >> 2, c1 = (b1 & 3) * 8;

    const float* gA0 = X + (size_t)(m0 + r0) * HD + c0;
    const float* gA1 = X + (size_t)(m0 + r1) * HD + c1;
    const float* gB0 = W + (size_t)(n0 + r0) * HD + c0;
    const float* gB1 = W + (size_t)(n0 + r1) * HD + c1;

    floatx4 acc[4][4];
#pragma unroll
    for (int i = 0; i < 4; ++i)
#pragma unroll
        for (int j = 0; j < 4; ++j)
            acc[i][j] = (floatx4){0.f, 0.f, 0.f, 0.f};

    float4 a0l = *(const float4*)(gA0);     float4 a0h = *(const float4*)(gA0 + 4);
    float4 a1l = *(const float4*)(gA1);     float4 a1h = *(const float4*)(gA1 + 4);
    float4 w0l = *(const float4*)(gB0);     float4 w0h = *(const float4*)(gB0 + 4);
    float4 w1l = *(const float4*)(gB1);     float4 w1h = *(const float4*)(gB1 + 4);

    for (int kt = 0; kt < 32; ++kt) {
        *(bf16x8*)(As + r0 * 32 + c0) = cvt8(a0l, a0h);
        *(bf16x8*)(As + r1 * 32 + c1) = cvt8(a1l, a1h);
        *(bf16x8*)(Bs + r0 * 32 + c0) = cvt8(w0l, w0h);
        *(bf16x8*)(Bs + r1 * 32 + c1) = cvt8(w1l, w1h);
        __syncthreads();

        if (kt + 1 < 32) {
            const int k0 = (kt + 1) * 32;
            a0l = *(const float4*)(gA0 + k0);  a0h = *(const float4*)(gA0 + k0 + 4);
            a1l = *(const float4*)(gA1 + k0);  a1h = *(const float4*)(gA1 + k0 + 4);
            w0l = *(const float4*)(gB0 + k0);  w0h = *(const float4*)(gB0 + k0 + 4);
            w1l = *(const float4*)(gB1 + k0);  w1h = *(const float4*)(gB1 + k0 + 4);
        }

        bf16x8 af[4], bfr[4];
#pragma unroll
        for (int t = 0; t < 4; ++t) {
            af[t]  = *(const bf16x8*)(As + (wm * 64 + t * 16 + l15) * 32 + quad * 8);
            bfr[t] = *(const bf16x8*)(Bs + (wn * 64 + t * 16 + l15) * 32 + quad * 8);
        }
#pragma unroll
        for (int i = 0; i < 4; ++i)
#pragma unroll
            for (int j = 0; j < 4; ++j)
                acc[i][j] = __builtin_amdgcn_mfma_f32_16x16x32_bf16(
                    af[i], bfr[j], acc[i][j], 0, 0, 0);
        __syncthreads();
    }

    // Epilogue: bias + RoPE + scatter. C/D: col=lane&15, row=quad*4+reg.
#pragma unroll
    for (int i = 0; i < 4; ++i) {
        const int mrow_base = m0 + wm * 64 + i * 16 + quad * 4;
#pragma unroll
        for (int j = 0; j < 2; ++j) {
            const int n1 = n0 + wn * 64 + j * 16 + l15;    // dim in [0,32)
            const int n2 = n1 + 32;
            const float b1 = bias[n1];
            const float b2 = bias[n2];
            const int which = n1 >> 10;          // 0=q 1=k 2=v
            const int hd    = n1 & 1023;
            const int head  = hd >> 6;
            const int dim   = hd & 63;           // < 32 by construction
            const float inv_freq = expf(-(float)dim * 0.28782313662425572f);
            bf16_t* outp = (which == 0) ? qws : (which == 1) ? kws : vws;
#pragma unroll
            for (int r = 0; r < 4; ++r) {
                const int mrow = mrow_base + r;
                const int s    = mrow & (S_LEN - 1);
                const int bb   = mrow >> 11;
                float x1 = acc[i][j][r]     + b1;
                float x2 = acc[i][j + 2][r] + b2;
                float o1, o2;
                if (which < 2) {
                    const float ang = (float)s * inv_freq;
                    const float cs = cosf(ang);
                    const float sn = sinf(ang);
                    o1 = x1 * cs - x2 * sn;
                    o2 = x2 * cs + x1 * sn;
                } else {
                    o1 = x1; o2 = x2;
                }
                const size_t off = ((size_t)(bb * NHEAD + head) * S_LEN + s) * DHEAD + dim;
                outp[off]      = f2bf(o1);
                outp[off + 32] = f2bf(o2);
            }
        }
    }
}

// ---------------------------------------------------------------------------
// Kernel 1b: one-shot V transpose [b][h][s][d] -> [b][h][d][s]. Each block
// does one (bh, 64-t tile). Output row d = exactly one 128-B cache line,
// covered contiguously by 4 consecutive lanes -> fully coalesced stores
// (unlike round-4's 2-B scatters). LDS 64x64 tile, stride 66 (2-way free
// writes, <=4-way scalar gather reads).
// ---------------------------------------------------------------------------
__global__ __launch_bounds__(256, 4)
void vtrans_kernel(const bf16_t* __restrict__ vsd, bf16_t* __restrict__ vds)
{
    __shared__ bf16_t T[64 * 66];
    const int tid = threadIdx.x;
    const int tt  = blockIdx.x;           // t-tile 0..31
    const int bh  = blockIdx.y;           // 0..63
    const size_t baseS = (size_t)bh * S_LEN * DHEAD + (size_t)tt * 64 * DHEAD;
    const size_t baseT = (size_t)bh * DHEAD * S_LEN + (size_t)tt * 64;

    {
        const int row = tid >> 2, col = (tid & 3) * 16;
        *(uint4*)(T + row * 66 + col)     = *(const uint4*)(vsd + baseS + (size_t)row * DHEAD + col);
        *(uint4*)(T + row * 66 + col + 8) = *(const uint4*)(vsd + baseS + (size_t)row * DHEAD + col + 8);
    }
    __syncthreads();
    {
        const int d = tid >> 2, s0 = (tid & 3) * 16;
        bf16_t buf[16];
#pragma unroll
        for (int m = 0; m < 16; ++m) buf[m] = T[(s0 + m) * 66 + d];
        *(uint4*)(vds + baseT + (size_t)d * S_LEN + s0)     = *(uint4*)(buf);
        *(uint4*)(vds + baseT + (size_t)d * S_LEN + s0 + 8) = *(uint4*)(buf + 8);
    }
}

// ---------------------------------------------------------------------------
// Kernel 2: flash attention. Block = (bh, 128 q-rows); 4 waves x 32 q-rows.
// Q fragments persist in registers. K [t][d] and V^T [d][t] (from vtrans)
// both staged coalesced uint4 -> b128 LDS, stride 72; all fragment reads
// b128. P round-trips wave-private stride-76 slab. exp2-based softmax
// (log2e folded into QK scale).
// ---------------------------------------------------------------------------
#define STK 72
#define STP 76
#define QKSCALE 0.1803368801111204f   // 0.125 * log2(e)

__global__ __launch_bounds__(256, 3)
void attn_kernel(const bf16_t* __restrict__ qws, const bf16_t* __restrict__ kws,
                 const bf16_t* __restrict__ vtws, float* __restrict__ out)
{
    __shared__ bf16_t Ks[64 * STK];    // 9216 B
    __shared__ bf16_t Vs[64 * STK];    // 9216 B  (V^T: [d][t])
    __shared__ bf16_t Ps[128 * STP];   // 19456 B (wave-private 32-row slabs)

    const int tid  = threadIdx.x;
    const int wave = tid >> 6;
    const int lane = tid & 63;
    const int l15  = lane & 15;
    const int quad = lane >> 4;
    const int qt   = blockIdx.x;          // 0..15 (128 q-rows each)
    const int bh   = blockIdx.y;          // 0..63
    const size_t baseS = (size_t)bh * S_LEN * DHEAD;   // q,k: [s][d]
    const size_t baseV = (size_t)bh * DHEAD * S_LEN;   // v^T: [d][s]
    const int q0 = qt * 128 + wave * 32;

    // Q fragments: persist across the whole loop. A[m=q][k=d].
    bf16x8 aq[2][2];
#pragma unroll
    for (int qsub = 0; qsub < 2; ++qsub)
#pragma unroll
        for (int kb = 0; kb < 2; ++kb)
            aq[qsub][kb] = *(const bf16x8*)(qws + baseS +
                (size_t)(q0 + qsub * 16 + l15) * DHEAD + kb * 32 + quad * 8);

    // staging coords: 64 rows x 64 cols, 2 x uint4 per thread per matrix
    const int srow = tid >> 2;
    const int scol = (tid & 3) * 8;

    uint4 kreg[2], vreg[2];
#pragma unroll
    for (int jj = 0; jj < 2; ++jj) {
        kreg[jj] = *(const uint4*)(kws  + baseS + (size_t)srow * DHEAD + scol + jj * 32);
        vreg[jj] = *(const uint4*)(vtws + baseV + (size_t)srow * S_LEN + scol + jj * 32);
    }

    float m_i[2][4], l_i[2][4], alpha[2][4];
    floatx4 o_acc[2][4];
#pragma unroll
    for (int qsub = 0; qsub < 2; ++qsub) {
#pragma unroll
        for (int r = 0; r < 4; ++r) { m_i[qsub][r] = -1e30f; l_i[qsub][r] = 0.0f; }
#pragma unroll
        for (int dt = 0; dt < 4; ++dt) o_acc[qsub][dt] = (floatx4){0.f, 0.f, 0.f, 0.f};
    }

    for (int kt = 0; kt < 32; ++kt) {
        // write prefetched tile to LDS, both coalesced b128
#pragma unroll
        for (int jj = 0; jj < 2; ++jj) {
            *(uint4*)(Ks + srow * STK + scol + jj * 32) = kreg[jj];
            *(uint4*)(Vs + srow * STK + scol + jj * 32) = vreg[jj];
        }
        __syncthreads();

        // prefetch next tile
        if (kt + 1 < 32) {
            const int t0 = (kt + 1) * 64;
#pragma unroll
            for (int jj = 0; jj < 2; ++jj) {
                kreg[jj] = *(const uint4*)(kws  + baseS + (size_t)(t0 + srow) * DHEAD + scol + jj * 32);
                vreg[jj] = *(const uint4*)(vtws + baseV + (size_t)srow * S_LEN + t0 + scol + jj * 32);
            }
        }

        // K fragments: B[n=t][k=d]
        bf16x8 bk[2][4];
#pragma unroll
        for (int kb = 0; kb < 2; ++kb)
#pragma unroll
            for (int nt = 0; nt < 4; ++nt)
                bk[kb][nt] = *(const bf16x8*)(Ks + (nt * 16 + l15) * STK + kb * 32 + quad * 8);

        // scores (in log2 units: folded 0.125*log2e)
        floatx4 sc[2][4];
#pragma unroll
        for (int qsub = 0; qsub < 2; ++qsub)
#pragma unroll
            for (int nt = 0; nt < 4; ++nt) {
                floatx4 s4 = (floatx4){0.f, 0.f, 0.f, 0.f};
#pragma unroll
                for (int kb = 0; kb < 2; ++kb)
                    s4 = __builtin_amdgcn_mfma_f32_16x16x32_bf16(
                        aq[qsub][kb], bk[kb][nt], s4, 0, 0, 0);
                sc[qsub][nt] = s4 * QKSCALE;
            }

        // online softmax (base-2) + P store (wave-private Ps slab)
#pragma unroll
        for (int qsub = 0; qsub < 2; ++qsub) {
            float mnew[4], rsum[4];
#pragma unroll
            for (int r = 0; r < 4; ++r) {
                float mx = fmaxf(fmaxf(sc[qsub][0][r], sc[qsub][1][r]),
                                 fmaxf(sc[qsub][2][r], sc[qsub][3][r]));
#pragma unroll
                for (int off = 1; off < 16; off <<= 1)
                    mx = fmaxf(mx, __shfl_xor(mx, off, 64));
                mnew[r]        = fmaxf(m_i[qsub][r], mx);
                alpha[qsub][r] = exp2f(m_i[qsub][r] - mnew[r]);
                rsum[r]        = 0.0f;
            }
#pragma unroll
            for (int nt = 0; nt < 4; ++nt)
#pragma unroll
                for (int r = 0; r < 4; ++r) {
                    const float p = exp2f(sc[qsub][nt][r] - mnew[r]);
                    const bf16_t pb = f2bf(p);
                    rsum[r] += bf2f(pb);
                    Ps[(wave * 32 + qsub * 16 + quad * 4 + r) * STP + nt * 16 + l15] = pb;
                }
#pragma unroll
            for (int r = 0; r < 4; ++r) {
                float sm = rsum[r];
#pragma unroll
                for (int off = 1; off < 16; off <<= 1)
                    sm += __shfl_xor(sm, off, 64);
                l_i[qsub][r] = l_i[qsub][r] * alpha[qsub][r] + sm;
                m_i[qsub][r] = mnew[r];
            }
        }

        // rescale O
#pragma unroll
        for (int qsub = 0; qsub < 2; ++qsub)
#pragma unroll
            for (int dt = 0; dt < 4; ++dt)
#pragma unroll
                for (int r = 0; r < 4; ++r)
                    o_acc[qsub][dt][r] *= alpha[qsub][r];

        // O += P V : A = P (LDS), B = V^T (Vs, [d][t]) — all b128 reads
#pragma unroll
        for (int kb = 0; kb < 2; ++kb) {
            bf16x8 bv[4];
#pragma unroll
            for (int dt = 0; dt < 4; ++dt)
                bv[dt] = *(const bf16x8*)(Vs + (dt * 16 + l15) * STK + kb * 32 + quad * 8);
#pragma unroll
            for (int qsub = 0; qsub < 2; ++qsub) {
                const int pbase = (wave * 32 + qsub * 16 + l15) * STP + kb * 32 + quad * 8;
                bf16x4 plo = *(const bf16x4*)(Ps + pbase);
                bf16x4 phi = *(const bf16x4*)(Ps + pbase + 4);
                bf16x8 ap = __builtin_shufflevector(plo, phi, 0, 1, 2, 3, 4, 5, 6, 7);
#pragma unroll
                for (int dt = 0; dt < 4; ++dt)
                    o_acc[qsub][dt] = __builtin_amdgcn_mfma_f32_16x16x32_bf16(
                        ap, bv[dt], o_acc[qsub][dt], 0, 0, 0);
            }
        }
        __syncthreads();
    }

    // normalize + store out[b][s][h*64+d] (fp32)
    const int bb = bh >> 4, hh = bh & 15;
#pragma unroll
    for (int qsub = 0; qsub < 2; ++qsub)
#pragma unroll
        for (int r = 0; r < 4; ++r) {
            const float inv = 1.0f / l_i[qsub][r];
            const int s = q0 + qsub * 16 + quad * 4 + r;
            const size_t off0 = ((size_t)(bb * S_LEN + s)) * HD + hh * DHEAD;
#pragma unroll
            for (int dt = 0; dt < 4; ++dt)
                out[off0 + dt * 16 + l15] = o_acc[qsub][dt][r] * inv;
        }
}

extern "C" void kernel_launch(void* const* d_in, const int* in_sizes, int n_in,
                              void* d_out, int out_size, void* d_ws, size_t ws_size,
                              hipStream_t stream) {
    const float* X    = (const float*)d_in[0];   // (4,2048,1024) fp32
    const float* W    = (const float*)d_in[1];   // (3072,1024) fp32
    const float* bias = (const float*)d_in[2];   // (3072,) fp32
    float* out = (float*)d_out;                  // (4,2048,1024) fp32

    const size_t per = (size_t)B_SZ * NHEAD * S_LEN * DHEAD;   // 8.39M elems
    bf16_t* qws  = (bf16_t*)d_ws;
    bf16_t* kws  = qws + per;
    bf16_t* vtws = kws + per;                 // V^T [b][h][d][s]
    bf16_t* vtmp = (bf16_t*)d_out;            // V [s][d] staged in out buffer
                                              // (overwritten by attn later)

    qkv_rope_kernel<<<dim3(N3 / 128, M_ROWS / 128), 256, 0, stream>>>(
        X, W, bias, qws, kws, vtmp);
    vtrans_kernel<<<dim3(S_LEN / 64, B_SZ * NHEAD), 256, 0, stream>>>(
        vtmp, vtws);
    attn_kernel<<<dim3(S_LEN / 128, B_SZ * NHEAD), 256, 0, stream>>>(
        qws, kws, vtws, out);
}

// Round 7
// 415.838 us; speedup vs baseline: 1.1177x; 1.1177x over previous
//
#include <hip/hip_runtime.h>
#include <hip/hip_bf16.h>
#include <math.h>

// Problem constants (B=4, S=2048, Hd=1024, h=16, d=64). fp32 in/out per the
// reference; bf16 internally (MFMA) with fp32 accumulation.
#define B_SZ   4
#define S_LEN  2048
#define HD     1024
#define NHEAD  16
#define DHEAD  64
#define N3     3072          // 3*Hd
#define M_ROWS 8192          // B*S

typedef __bf16 bf16_t;
typedef __bf16 bf16x4 __attribute__((ext_vector_type(4)));
typedef __bf16 bf16x8 __attribute__((ext_vector_type(8)));
typedef float  floatx4 __attribute__((ext_vector_type(4)));

__device__ __forceinline__ float bf2f(bf16_t x) { return (float)x; }
__device__ __forceinline__ bf16_t f2bf(float f) { return (bf16_t)f; }  // RNE fptrunc
__device__ __forceinline__ float fexp2(float x) { return __builtin_amdgcn_exp2f(x); }

__device__ __forceinline__ bf16x8 cvt8(const float4 lo, const float4 hi) {
    bf16x8 r;
    r[0] = (bf16_t)lo.x; r[1] = (bf16_t)lo.y; r[2] = (bf16_t)lo.z; r[3] = (bf16_t)lo.w;
    r[4] = (bf16_t)hi.x; r[5] = (bf16_t)hi.y; r[6] = (bf16_t)hi.z; r[7] = (bf16_t)hi.w;
    return r;
}

// ---------------------------------------------------------------------------
// Kernel 1 (round-3 version, measured ~163 us): qkv = X @ W^T + b, fused RoPE
// on q,k; scatter bf16 [b][h][s][d] for q,k,v (contiguous along dim across
// lanes -> stores merge). [d][s] direct scatter banned (round-4: 3 GB write
// amp); split-V via d_out banned (round-6: +174 MB traffic in attn window).
// ---------------------------------------------------------------------------
__global__ __launch_bounds__(256, 3)
void qkv_rope_kernel(const float* __restrict__ X, const float* __restrict__ W,
                     const float* __restrict__ bias,
                     bf16_t* __restrict__ qws, bf16_t* __restrict__ kws,
                     bf16_t* __restrict__ vws)
{
    __shared__ bf16_t As[128 * 32];   // 8 KB, [row][32] bf16 (16-dword rows)
    __shared__ bf16_t Bs[128 * 32];   // 8 KB

    const int tid  = threadIdx.x;
    const int wave = tid >> 6;
    const int lane = tid & 63;
    const int l15  = lane & 15;
    const int quad = lane >> 4;
    const int wm   = wave >> 1;
    const int wn   = wave & 1;
    const int m0   = blockIdx.y * 128;
    const int n0   = blockIdx.x * 128;

    const int b0   = tid;
    const int b1   = tid + 256;
    const int r0   = b0 >> 2, c0 = (b0 & 3) * 8;
    const int r1   = b1 >> 2, c1 = (b1 & 3) * 8;

    const float* gA0 = X + (size_t)(m0 + r0) * HD + c0;
    const float* gA1 = X + (size_t)(m0 + r1) * HD + c1;
    const float* gB0 = W + (size_t)(n0 + r0) * HD + c0;
    const float* gB1 = W + (size_t)(n0 + r1) * HD + c1;

    floatx4 acc[4][4];
#pragma unroll
    for (int i = 0; i < 4; ++i)
#pragma unroll
        for (int j = 0; j < 4; ++j)
            acc[i][j] = (floatx4){0.f, 0.f, 0.f, 0.f};

    float4 a0l = *(const float4*)(gA0);     float4 a0h = *(const float4*)(gA0 + 4);
    float4 a1l = *(const float4*)(gA1);     float4 a1h = *(const float4*)(gA1 + 4);
    float4 w0l = *(const float4*)(gB0);     float4 w0h = *(const float4*)(gB0 + 4);
    float4 w1l = *(const float4*)(gB1);     float4 w1h = *(const float4*)(gB1 + 4);

    for (int kt = 0; kt < 32; ++kt) {
        *(bf16x8*)(As + r0 * 32 + c0) = cvt8(a0l, a0h);
        *(bf16x8*)(As + r1 * 32 + c1) = cvt8(a1l, a1h);
        *(bf16x8*)(Bs + r0 * 32 + c0) = cvt8(w0l, w0h);
        *(bf16x8*)(Bs + r1 * 32 + c1) = cvt8(w1l, w1h);
        __syncthreads();

        if (kt + 1 < 32) {
            const int k0 = (kt + 1) * 32;
            a0l = *(const float4*)(gA0 + k0);  a0h = *(const float4*)(gA0 + k0 + 4);
            a1l = *(const float4*)(gA1 + k0);  a1h = *(const float4*)(gA1 + k0 + 4);
            w0l = *(const float4*)(gB0 + k0);  w0h = *(const float4*)(gB0 + k0 + 4);
            w1l = *(const float4*)(gB1 + k0);  w1h = *(const float4*)(gB1 + k0 + 4);
        }

        bf16x8 af[4], bfr[4];
#pragma unroll
        for (int t = 0; t < 4; ++t) {
            af[t]  = *(const bf16x8*)(As + (wm * 64 + t * 16 + l15) * 32 + quad * 8);
            bfr[t] = *(const bf16x8*)(Bs + (wn * 64 + t * 16 + l15) * 32 + quad * 8);
        }
#pragma unroll
        for (int i = 0; i < 4; ++i)
#pragma unroll
            for (int j = 0; j < 4; ++j)
                acc[i][j] = __builtin_amdgcn_mfma_f32_16x16x32_bf16(
                    af[i], bfr[j], acc[i][j], 0, 0, 0);
        __syncthreads();
    }

    // Epilogue: bias + RoPE + scatter. C/D: col=lane&15, row=quad*4+reg.
#pragma unroll
    for (int i = 0; i < 4; ++i) {
        const int mrow_base = m0 + wm * 64 + i * 16 + quad * 4;
#pragma unroll
        for (int j = 0; j < 2; ++j) {
            const int n1 = n0 + wn * 64 + j * 16 + l15;    // dim in [0,32)
            const int n2 = n1 + 32;
            const float b1 = bias[n1];
            const float b2 = bias[n2];
            const int which = n1 >> 10;          // 0=q 1=k 2=v
            const int hd    = n1 & 1023;
            const int head  = hd >> 6;
            const int dim   = hd & 63;           // < 32 by construction
            const float inv_freq = expf(-(float)dim * 0.28782313662425572f);
            bf16_t* outp = (which == 0) ? qws : (which == 1) ? kws : vws;
#pragma unroll
            for (int r = 0; r < 4; ++r) {
                const int mrow = mrow_base + r;
                const int s    = mrow & (S_LEN - 1);
                const int bb   = mrow >> 11;
                float x1 = acc[i][j][r]     + b1;
                float x2 = acc[i][j + 2][r] + b2;
                float o1, o2;
                if (which < 2) {
                    const float ang = (float)s * inv_freq;
                    const float cs = cosf(ang);
                    const float sn = sinf(ang);
                    o1 = x1 * cs - x2 * sn;
                    o2 = x2 * cs + x1 * sn;
                } else {
                    o1 = x1; o2 = x2;
                }
                const size_t off = ((size_t)(bb * NHEAD + head) * S_LEN + s) * DHEAD + dim;
                outp[off]      = f2bf(o1);
                outp[off + 32] = f2bf(o2);
            }
        }
    }
}

// ---------------------------------------------------------------------------
// Kernel 2: flash attention (round-5 structure, measured 254 us).
// Block = (bh, 128 q-rows); 4 waves x 32 q-rows. grid=(bh, qt) so linear
// block id % 8 == bh % 8: all 16 qt blocks of one bh share ONE XCD's L2
// (K+V working set 512 KB << 4 MB) -> cuts the ~3.8x K/V HBM re-fetch.
// Q frags persist in regs. K staged row-major (stride 72). V transposed
// in-LDS to Vt [d][t] stride 70 (conflict-free writes: banks
// {0,8,16,24}+srow/2 cover all 32 exactly once). P in wave-private
// stride-76 slab. Softmax in base-2 via v_exp_f32 (scale pre-folded).
// ---------------------------------------------------------------------------
#define STK 72
#define STV 70
#define STP 76
#define QKSCALE 0.1803368801111204f   // 0.125 * log2(e)

__device__ __forceinline__ bf16x8 ldsT8(const bf16_t* p) {
    uint4 u;
    u.x = *(const unsigned*)(p);
    u.y = *(const unsigned*)(p + 2);
    u.z = *(const unsigned*)(p + 4);
    u.w = *(const unsigned*)(p + 6);
    return __builtin_bit_cast(bf16x8, u);
}

__global__ __launch_bounds__(256, 3)
void attn_kernel(const bf16_t* __restrict__ qws, const bf16_t* __restrict__ kws,
                 const bf16_t* __restrict__ vws, float* __restrict__ out)
{
    __shared__ bf16_t Ks[64 * STK];    // 9216 B
    __shared__ bf16_t Vt[64 * STV];    // 8960 B  (V^T: [d][t], stride 70)
    __shared__ bf16_t Ps[128 * STP];   // 19456 B (wave-private 32-row slabs)

    const int tid  = threadIdx.x;
    const int wave = tid >> 6;
    const int lane = tid & 63;
    const int l15  = lane & 15;
    const int quad = lane >> 4;
    const int bh   = blockIdx.x;          // 0..63  (x so that XCD = bh % 8)
    const int qt   = blockIdx.y;          // 0..15 (128 q-rows each)
    const size_t baseS = (size_t)bh * S_LEN * DHEAD;   // q,k,v: [s][d]
    const int q0 = qt * 128 + wave * 32;

    // Q fragments: persist across the whole loop. A[m=q][k=d].
    bf16x8 aq[2][2];
#pragma unroll
    for (int qsub = 0; qsub < 2; ++qsub)
#pragma unroll
        for (int kb = 0; kb < 2; ++kb)
            aq[qsub][kb] = *(const bf16x8*)(qws + baseS +
                (size_t)(q0 + qsub * 16 + l15) * DHEAD + kb * 32 + quad * 8);

    // staging coords: 64 rows x 64 cols, 2 x uint4 per thread per matrix
    const int srow = tid >> 2;
    const int scol = (tid & 3) * 8;

    uint4 kreg[2], vreg[2];
#pragma unroll
    for (int jj = 0; jj < 2; ++jj) {
        kreg[jj] = *(const uint4*)(kws + baseS + (size_t)srow * DHEAD + scol + jj * 32);
        vreg[jj] = *(const uint4*)(vws + baseS + (size_t)srow * DHEAD + scol + jj * 32);
    }

    float m_i[2][4], l_i[2][4], alpha[2][4];
    floatx4 o_acc[2][4];
#pragma unroll
    for (int qsub = 0; qsub < 2; ++qsub) {
#pragma unroll
        for (int r = 0; r < 4; ++r) { m_i[qsub][r] = -1e30f; l_i[qsub][r] = 0.0f; }
#pragma unroll
        for (int dt = 0; dt < 4; ++dt) o_acc[qsub][dt] = (floatx4){0.f, 0.f, 0.f, 0.f};
    }

    for (int kt = 0; kt < 32; ++kt) {
        // write prefetched tile to LDS: K row-major, V transposed
#pragma unroll
        for (int jj = 0; jj < 2; ++jj) {
            *(uint4*)(Ks + srow * STK + scol + jj * 32) = kreg[jj];
            bf16_t vv[8];
            *(uint4*)vv = vreg[jj];
#pragma unroll
            for (int e = 0; e < 8; ++e)
                Vt[(scol + jj * 32 + e) * STV + srow] = vv[e];
        }
        __syncthreads();

        // prefetch next tile
        if (kt + 1 < 32) {
            const int t0 = (kt + 1) * 64;
#pragma unroll
            for (int jj = 0; jj < 2; ++jj) {
                kreg[jj] = *(const uint4*)(kws + baseS + (size_t)(t0 + srow) * DHEAD + scol + jj * 32);
                vreg[jj] = *(const uint4*)(vws + baseS + (size_t)(t0 + srow) * DHEAD + scol + jj * 32);
            }
        }

        // K fragments: B[n=t][k=d]
        bf16x8 bk[2][4];
#pragma unroll
        for (int kb = 0; kb < 2; ++kb)
#pragma unroll
            for (int nt = 0; nt < 4; ++nt)
                bk[kb][nt] = *(const bf16x8*)(Ks + (nt * 16 + l15) * STK + kb * 32 + quad * 8);

        // scores (base-2 units: 0.125*log2e folded)
        floatx4 sc[2][4];
#pragma unroll
        for (int qsub = 0; qsub < 2; ++qsub)
#pragma unroll
            for (int nt = 0; nt < 4; ++nt) {
                floatx4 s4 = (floatx4){0.f, 0.f, 0.f, 0.f};
#pragma unroll
                for (int kb = 0; kb < 2; ++kb)
                    s4 = __builtin_amdgcn_mfma_f32_16x16x32_bf16(
                        aq[qsub][kb], bk[kb][nt], s4, 0, 0, 0);
                sc[qsub][nt] = s4 * QKSCALE;
            }

        // online softmax (base-2, v_exp_f32) + P store (wave-private slab)
#pragma unroll
        for (int qsub = 0; qsub < 2; ++qsub) {
            float mnew[4], rsum[4];
#pragma unroll
            for (int r = 0; r < 4; ++r) {
                float mx = fmaxf(fmaxf(sc[qsub][0][r], sc[qsub][1][r]),
                                 fmaxf(sc[qsub][2][r], sc[qsub][3][r]));
#pragma unroll
                for (int off = 1; off < 16; off <<= 1)
                    mx = fmaxf(mx, __shfl_xor(mx, off, 64));
                mnew[r]        = fmaxf(m_i[qsub][r], mx);
                alpha[qsub][r] = fexp2(m_i[qsub][r] - mnew[r]);
                rsum[r]        = 0.0f;
            }
#pragma unroll
            for (int nt = 0; nt < 4; ++nt)
#pragma unroll
                for (int r = 0; r < 4; ++r) {
                    const float p = fexp2(sc[qsub][nt][r] - mnew[r]);
                    const bf16_t pb = f2bf(p);
                    rsum[r] += bf2f(pb);
                    Ps[(wave * 32 + qsub * 16 + quad * 4 + r) * STP + nt * 16 + l15] = pb;
                }
#pragma unroll
            for (int r = 0; r < 4; ++r) {
                float sm = rsum[r];
#pragma unroll
                for (int off = 1; off < 16; off <<= 1)
                    sm += __shfl_xor(sm, off, 64);
                l_i[qsub][r] = l_i[qsub][r] * alpha[qsub][r] + sm;
                m_i[qsub][r] = mnew[r];
            }
        }

        // rescale O
#pragma unroll
        for (int qsub = 0; qsub < 2; ++qsub)
#pragma unroll
            for (int dt = 0; dt < 4; ++dt)
#pragma unroll
                for (int r = 0; r < 4; ++r)
                    o_acc[qsub][dt][r] *= alpha[qsub][r];

        // O += P V : A = P (LDS), B = V^T (Vt, [d][t])
#pragma unroll
        for (int kb = 0; kb < 2; ++kb) {
            bf16x8 bv[4];
#pragma unroll
            for (int dt = 0; dt < 4; ++dt)
                bv[dt] = ldsT8(Vt + (dt * 16 + l15) * STV + kb * 32 + quad * 8);
#pragma unroll
            for (int qsub = 0; qsub < 2; ++qsub) {
                const int pbase = (wave * 32 + qsub * 16 + l15) * STP + kb * 32 + quad * 8;
                bf16x4 plo = *(const bf16x4*)(Ps + pbase);
                bf16x4 phi = *(const bf16x4*)(Ps + pbase + 4);
                bf16x8 ap = __builtin_shufflevector(plo, phi, 0, 1, 2, 3, 4, 5, 6, 7);
#pragma unroll
                for (int dt = 0; dt < 4; ++dt)
                    o_acc[qsub][dt] = __builtin_amdgcn_mfma_f32_16x16x32_bf16(
                        ap, bv[dt], o_acc[qsub][dt], 0, 0, 0);
            }
        }
        __syncthreads();
    }

    // normalize + store out[b][s][h*64+d] (fp32)
    const int bb = bh >> 4, hh = bh & 15;
#pragma unroll
    for (int qsub = 0; qsub < 2; ++qsub)
#pragma unroll
        for (int r = 0; r < 4; ++r) {
            const float inv = 1.0f / l_i[qsub][r];
            const int s = q0 + qsub * 16 + quad * 4 + r;
            const size_t off0 = ((size_t)(bb * S_LEN + s)) * HD + hh * DHEAD;
#pragma unroll
            for (int dt = 0; dt < 4; ++dt)
                out[off0 + dt * 16 + l15] = o_acc[qsub][dt][r] * inv;
        }
}

extern "C" void kernel_launch(void* const* d_in, const int* in_sizes, int n_in,
                              void* d_out, int out_size, void* d_ws, size_t ws_size,
                              hipStream_t stream) {
    const float* X    = (const float*)d_in[0];   // (4,2048,1024) fp32
    const float* W    = (const float*)d_in[1];   // (3072,1024) fp32
    const float* bias = (const float*)d_in[2];   // (3072,) fp32
    float* out = (float*)d_out;                  // (4,2048,1024) fp32

    const size_t per = (size_t)B_SZ * NHEAD * S_LEN * DHEAD;   // 8.39M elems
    bf16_t* qws = (bf16_t*)d_ws;
    bf16_t* kws = qws + per;
    bf16_t* vws = kws + per;

    qkv_rope_kernel<<<dim3(N3 / 128, M_ROWS / 128), 256, 0, stream>>>(
        X, W, bias, qws, kws, vws);
    attn_kernel<<<dim3(B_SZ * NHEAD, S_LEN / 128), 256, 0, stream>>>(
        qws, kws, vws, out);
}

// Round 8
// 404.772 us; speedup vs baseline: 1.1482x; 1.0273x over previous
//
#include <hip/hip_runtime.h>
#include <hip/hip_bf16.h>
#include <math.h>

// Problem constants (B=4, S=2048, Hd=1024, h=16, d=64). fp32 in/out per the
// reference; bf16 internally (MFMA) with fp32 accumulation.
#define B_SZ   4
#define S_LEN  2048
#define HD     1024
#define NHEAD  16
#define DHEAD  64
#define N3     3072          // 3*Hd
#define M_ROWS 8192          // B*S

typedef __bf16 bf16_t;
typedef __bf16 bf16x4 __attribute__((ext_vector_type(4)));
typedef __bf16 bf16x8 __attribute__((ext_vector_type(8)));
typedef float  floatx4 __attribute__((ext_vector_type(4)));

__device__ __forceinline__ float bf2f(bf16_t x) { return (float)x; }
__device__ __forceinline__ bf16_t f2bf(float f) { return (bf16_t)f; }  // RNE fptrunc
__device__ __forceinline__ float fexp2(float x) { return __builtin_amdgcn_exp2f(x); }

#define QKSCALE 0.1803368801111204f   // 0.125 * log2(e), folded into K in k1

__device__ __forceinline__ bf16x8 cvt8(const float4 lo, const float4 hi) {
    bf16x8 r;
    r[0] = (bf16_t)lo.x; r[1] = (bf16_t)lo.y; r[2] = (bf16_t)lo.z; r[3] = (bf16_t)lo.w;
    r[4] = (bf16_t)hi.x; r[5] = (bf16_t)hi.y; r[6] = (bf16_t)hi.z; r[7] = (bf16_t)hi.w;
    return r;
}

// ---------------------------------------------------------------------------
// Kernel 1 (round-3 structure, ~165 us): qkv = X @ W^T + b, fused RoPE on
// q,k; K additionally pre-scaled by 0.125*log2(e) so attn's softmax runs in
// base-2 with no scale mul. Scatter bf16 [b][h][s][d] (contiguous along dim
// across lanes). [d][s] scatter banned (round-4: 3 GB write amp).
// ---------------------------------------------------------------------------
__global__ __launch_bounds__(256, 3)
void qkv_rope_kernel(const float* __restrict__ X, const float* __restrict__ W,
                     const float* __restrict__ bias,
                     bf16_t* __restrict__ qws, bf16_t* __restrict__ kws,
                     bf16_t* __restrict__ vws)
{
    __shared__ bf16_t As[128 * 32];   // 8 KB, [row][32] bf16 (16-dword rows)
    __shared__ bf16_t Bs[128 * 32];   // 8 KB

    const int tid  = threadIdx.x;
    const int wave = tid >> 6;
    const int lane = tid & 63;
    const int l15  = lane & 15;
    const int quad = lane >> 4;
    const int wm   = wave >> 1;
    const int wn   = wave & 1;
    const int m0   = blockIdx.y * 128;
    const int n0   = blockIdx.x * 128;

    const int b0   = tid;
    const int b1   = tid + 256;
    const int r0   = b0 >> 2, c0 = (b0 & 3) * 8;
    const int r1   = b1 >> 2, c1 = (b1 & 3) * 8;

    const float* gA0 = X + (size_t)(m0 + r0) * HD + c0;
    const float* gA1 = X + (size_t)(m0 + r1) * HD + c1;
    const float* gB0 = W + (size_t)(n0 + r0) * HD + c0;
    const float* gB1 = W + (size_t)(n0 + r1) * HD + c1;

    floatx4 acc[4][4];
#pragma unroll
    for (int i = 0; i < 4; ++i)
#pragma unroll
        for (int j = 0; j < 4; ++j)
            acc[i][j] = (floatx4){0.f, 0.f, 0.f, 0.f};

    float4 a0l = *(const float4*)(gA0);     float4 a0h = *(const float4*)(gA0 + 4);
    float4 a1l = *(const float4*)(gA1);     float4 a1h = *(const float4*)(gA1 + 4);
    float4 w0l = *(const float4*)(gB0);     float4 w0h = *(const float4*)(gB0 + 4);
    float4 w1l = *(const float4*)(gB1);     float4 w1h = *(const float4*)(gB1 + 4);

    for (int kt = 0; kt < 32; ++kt) {
        *(bf16x8*)(As + r0 * 32 + c0) = cvt8(a0l, a0h);
        *(bf16x8*)(As + r1 * 32 + c1) = cvt8(a1l, a1h);
        *(bf16x8*)(Bs + r0 * 32 + c0) = cvt8(w0l, w0h);
        *(bf16x8*)(Bs + r1 * 32 + c1) = cvt8(w1l, w1h);
        __syncthreads();

        if (kt + 1 < 32) {
            const int k0 = (kt + 1) * 32;
            a0l = *(const float4*)(gA0 + k0);  a0h = *(const float4*)(gA0 + k0 + 4);
            a1l = *(const float4*)(gA1 + k0);  a1h = *(const float4*)(gA1 + k0 + 4);
            w0l = *(const float4*)(gB0 + k0);  w0h = *(const float4*)(gB0 + k0 + 4);
            w1l = *(const float4*)(gB1 + k0);  w1h = *(const float4*)(gB1 + k0 + 4);
        }

        bf16x8 af[4], bfr[4];
#pragma unroll
        for (int t = 0; t < 4; ++t) {
            af[t]  = *(const bf16x8*)(As + (wm * 64 + t * 16 + l15) * 32 + quad * 8);
            bfr[t] = *(const bf16x8*)(Bs + (wn * 64 + t * 16 + l15) * 32 + quad * 8);
        }
#pragma unroll
        for (int i = 0; i < 4; ++i)
#pragma unroll
            for (int j = 0; j < 4; ++j)
                acc[i][j] = __builtin_amdgcn_mfma_f32_16x16x32_bf16(
                    af[i], bfr[j], acc[i][j], 0, 0, 0);
        __syncthreads();
    }

    // Epilogue: bias + RoPE + scatter. C/D: col=lane&15, row=quad*4+reg.
#pragma unroll
    for (int i = 0; i < 4; ++i) {
        const int mrow_base = m0 + wm * 64 + i * 16 + quad * 4;
#pragma unroll
        for (int j = 0; j < 2; ++j) {
            const int n1 = n0 + wn * 64 + j * 16 + l15;    // dim in [0,32)
            const int n2 = n1 + 32;
            const float b1 = bias[n1];
            const float b2 = bias[n2];
            const int which = n1 >> 10;          // 0=q 1=k 2=v (wave-uniform)
            const int hd    = n1 & 1023;
            const int head  = hd >> 6;
            const int dim   = hd & 63;           // < 32 by construction
            const float inv_freq = expf(-(float)dim * 0.28782313662425572f);
            bf16_t* outp = (which == 0) ? qws : (which == 1) ? kws : vws;
#pragma unroll
            for (int r = 0; r < 4; ++r) {
                const int mrow = mrow_base + r;
                const int s    = mrow & (S_LEN - 1);
                const int bb   = mrow >> 11;
                float x1 = acc[i][j][r]     + b1;
                float x2 = acc[i][j + 2][r] + b2;
                float o1, o2;
                if (which < 2) {
                    const float ang = (float)s * inv_freq;
                    float cs = cosf(ang);
                    float sn = sinf(ang);
                    if (which == 1) { cs *= QKSCALE; sn *= QKSCALE; }
                    o1 = x1 * cs - x2 * sn;
                    o2 = x2 * cs + x1 * sn;
                } else {
                    o1 = x1; o2 = x2;
                }
                const size_t off = ((size_t)(bb * NHEAD + head) * S_LEN + s) * DHEAD + dim;
                outp[off]      = f2bf(o1);
                outp[off + 32] = f2bf(o2);
            }
        }
    }
}

// ---------------------------------------------------------------------------
// Kernel 2: flash attention, operand-swapped QK^T (S^T = K Q^T) so each lane
// owns ONE q-row (q = lane&15): softmax needs only xor16/xor32 shuffles (2
// per reduction vs the old 4x4 butterfly = 64 ds_bpermute/kt-wave -> 16).
// P is written t-contiguous (b64 x8) into a [q][t] stride-72 slab and read
// back as b128 A-fragments (x4). V transposed in-LDS into a rotate-swizzled
// [d][t] stride-64 layout: writes conflict-free, reads b128 balanced.
// K pre-scaled by 0.125*log2e in k1 -> softmax in base-2, no muls.
// grid=(bh, qt): XCD L2 locality (round 7: FETCH 142->56 MB).
// ---------------------------------------------------------------------------
#define STK 72
#define STP 72

__global__ __launch_bounds__(256, 4)
void attn_kernel(const bf16_t* __restrict__ qws, const bf16_t* __restrict__ kws,
                 const bf16_t* __restrict__ vws, float* __restrict__ out)
{
    __shared__ bf16_t Ks[64 * STK];    // 9216 B  K [t][d]
    __shared__ bf16_t Vt[64 * 64];     // 8192 B  V^T [d][t], rotate-swizzled
    __shared__ bf16_t Ps[128 * STP];   // 18432 B P [q][t], wave-private rows

    const int tid  = threadIdx.x;
    const int wave = tid >> 6;
    const int lane = tid & 63;
    const int l15  = lane & 15;
    const int quad = lane >> 4;
    const int bh   = blockIdx.x;          // 0..63  (XCD = bh % 8)
    const int qt   = blockIdx.y;          // 0..15
    const size_t baseS = (size_t)bh * S_LEN * DHEAD;
    const int q0 = qt * 128 + wave * 32;

    // Q fragments (B-operand: n=q on lane&15, k=d on quad*8+j), persistent.
    bf16x8 aq[2][2];
#pragma unroll
    for (int qsub = 0; qsub < 2; ++qsub)
#pragma unroll
        for (int kb = 0; kb < 2; ++kb)
            aq[qsub][kb] = *(const bf16x8*)(qws + baseS +
                (size_t)(q0 + qsub * 16 + l15) * DHEAD + kb * 32 + quad * 8);

    // staging coords: 64 t-rows x 64 d-cols, 2 x uint4 per thread per matrix
    const int srow = tid >> 2;            // t
    const int scol = (tid & 3) * 8;       // d base

    uint4 kreg[2], vreg[2];
#pragma unroll
    for (int jj = 0; jj < 2; ++jj) {
        kreg[jj] = *(const uint4*)(kws + baseS + (size_t)srow * DHEAD + scol + jj * 32);
        vreg[jj] = *(const uint4*)(vws + baseS + (size_t)srow * DHEAD + scol + jj * 32);
    }

    float m_i[2] = {-1e30f, -1e30f};      // per-lane state for q = qsub*16+l15
    float l_i[2] = {0.f, 0.f};            // (replicated across quads)
    floatx4 o_acc[2][4];
#pragma unroll
    for (int qsub = 0; qsub < 2; ++qsub)
#pragma unroll
        for (int dt = 0; dt < 4; ++dt)
            o_acc[qsub][dt] = (floatx4){0.f, 0.f, 0.f, 0.f};

    for (int kt = 0; kt < 32; ++kt) {
        // --- stage K row-major; V transposed with rotate swizzle -----------
#pragma unroll
        for (int jj = 0; jj < 2; ++jj) {
            *(uint4*)(Ks + srow * STK + scol + jj * 32) = kreg[jj];
            bf16_t vv[8];
            *(uint4*)vv = vreg[jj];
            const int dbase = scol + jj * 32;
#pragma unroll
            for (int e = 0; e < 8; ++e) {
                const int d = dbase + e;
                const int trot = (srow + 16 * ((d >> 3) & 3)) & 63;
                Vt[d * 64 + trot] = vv[e];
            }
        }
        __syncthreads();

        // prefetch next tile
        if (kt + 1 < 32) {
            const int t0 = (kt + 1) * 64;
#pragma unroll
            for (int jj = 0; jj < 2; ++jj) {
                kreg[jj] = *(const uint4*)(kws + baseS + (size_t)(t0 + srow) * DHEAD + scol + jj * 32);
                vreg[jj] = *(const uint4*)(vws + baseS + (size_t)(t0 + srow) * DHEAD + scol + jj * 32);
            }
        }

        // --- S^T = K Q^T : C row = t (quad*4+r), col = q (l15) -------------
        floatx4 st[2][4];
#pragma unroll
        for (int qsub = 0; qsub < 2; ++qsub)
#pragma unroll
            for (int mt = 0; mt < 4; ++mt)
                st[qsub][mt] = (floatx4){0.f, 0.f, 0.f, 0.f};
#pragma unroll
        for (int kb = 0; kb < 2; ++kb)
#pragma unroll
            for (int mt = 0; mt < 4; ++mt) {
                bf16x8 ak = *(const bf16x8*)(Ks + (mt * 16 + l15) * STK + kb * 32 + quad * 8);
#pragma unroll
                for (int qsub = 0; qsub < 2; ++qsub)
                    st[qsub][mt] = __builtin_amdgcn_mfma_f32_16x16x32_bf16(
                        ak, aq[qsub][kb], st[qsub][mt], 0, 0, 0);
            }

        // --- online softmax: lane owns q = qsub*16+l15, 16 t-values local --
        float alphaL[2];
#pragma unroll
        for (int qsub = 0; qsub < 2; ++qsub) {
            float mx = st[qsub][0][0];
#pragma unroll
            for (int mt = 0; mt < 4; ++mt)
#pragma unroll
                for (int r = 0; r < 4; ++r)
                    mx = fmaxf(mx, st[qsub][mt][r]);
            mx = fmaxf(mx, __shfl_xor(mx, 16, 64));
            mx = fmaxf(mx, __shfl_xor(mx, 32, 64));
            const float mnew = fmaxf(m_i[qsub], mx);
            alphaL[qsub] = fexp2(m_i[qsub] - mnew);
            float rs = 0.f;
#pragma unroll
            for (int mt = 0; mt < 4; ++mt) {
                bf16x4 pb;
#pragma unroll
                for (int r = 0; r < 4; ++r) {
                    const float p = fexp2(st[qsub][mt][r] - mnew);
                    pb[r] = f2bf(p);
                    rs += bf2f(pb[r]);
                }
                *(bf16x4*)(Ps + (wave * 32 + qsub * 16 + l15) * STP + mt * 16 + quad * 4) = pb;
            }
            rs += __shfl_xor(rs, 16, 64);
            rs += __shfl_xor(rs, 32, 64);
            l_i[qsub] = l_i[qsub] * alphaL[qsub] + rs;
            m_i[qsub] = mnew;
        }

        // --- rescale O (alpha moved to C-layout rows via one shfl per r) ---
#pragma unroll
        for (int qsub = 0; qsub < 2; ++qsub)
#pragma unroll
            for (int r = 0; r < 4; ++r) {
                const float a = __shfl(alphaL[qsub], (lane & 48) | (quad * 4 + r), 64);
#pragma unroll
                for (int dt = 0; dt < 4; ++dt)
                    o_acc[qsub][dt][r] *= a;
            }

        // --- O += P V : A = P [q][t] (b128), B = V^T [d][t] (b128) ---------
#pragma unroll
        for (int kb = 0; kb < 2; ++kb) {
            bf16x8 bv[4];
#pragma unroll
            for (int dt = 0; dt < 4; ++dt) {
                const int d = dt * 16 + l15;
                const int trot = (kb * 32 + quad * 8 + 16 * ((d >> 3) & 3)) & 63;
                bv[dt] = *(const bf16x8*)(Vt + d * 64 + trot);
            }
#pragma unroll
            for (int qsub = 0; qsub < 2; ++qsub) {
                bf16x8 ap = *(const bf16x8*)(Ps + (wave * 32 + qsub * 16 + l15) * STP + kb * 32 + quad * 8);
#pragma unroll
                for (int dt = 0; dt < 4; ++dt)
                    o_acc[qsub][dt] = __builtin_amdgcn_mfma_f32_16x16x32_bf16(
                        ap, bv[dt], o_acc[qsub][dt], 0, 0, 0);
            }
        }
        __syncthreads();
    }

    // normalize + store out[b][s][h*64+d] (fp32); l transposed via shfl
    const int bb = bh >> 4, hh = bh & 15;
#pragma unroll
    for (int qsub = 0; qsub < 2; ++qsub)
#pragma unroll
        for (int r = 0; r < 4; ++r) {
            const float lv  = __shfl(l_i[qsub], (lane & 48) | (quad * 4 + r), 64);
            const float inv = 1.0f / lv;
            const int s = q0 + qsub * 16 + quad * 4 + r;
            const size_t off0 = ((size_t)(bb * S_LEN + s)) * HD + hh * DHEAD;
#pragma unroll
            for (int dt = 0; dt < 4; ++dt)
                out[off0 + dt * 16 + l15] = o_acc[qsub][dt][r] * inv;
        }
}

extern "C" void kernel_launch(void* const* d_in, const int* in_sizes, int n_in,
                              void* d_out, int out_size, void* d_ws, size_t ws_size,
                              hipStream_t stream) {
    const float* X    = (const float*)d_in[0];   // (4,2048,1024) fp32
    const float* W    = (const float*)d_in[1];   // (3072,1024) fp32
    const float* bias = (const float*)d_in[2];   // (3072,) fp32
    float* out = (float*)d_out;                  // (4,2048,1024) fp32

    const size_t per = (size_t)B_SZ * NHEAD * S_LEN * DHEAD;   // 8.39M elems
    bf16_t* qws = (bf16_t*)d_ws;
    bf16_t* kws = qws + per;
    bf16_t* vws = kws + per;

    qkv_rope_kernel<<<dim3(N3 / 128, M_ROWS / 128), 256, 0, stream>>>(
        X, W, bias, qws, kws, vws);
    attn_kernel<<<dim3(B_SZ * NHEAD, S_LEN / 128), 256, 0, stream>>>(
        qws, kws, vws, out);
}

// Round 9
// 343.809 us; speedup vs baseline: 1.3519x; 1.1773x over previous
//
#include <hip/hip_runtime.h>
#include <hip/hip_bf16.h>
#include <math.h>

// Problem constants (B=4, S=2048, Hd=1024, h=16, d=64). fp32 in/out per the
// reference; bf16 internally (MFMA) with fp32 accumulation.
#define B_SZ   4
#define S_LEN  2048
#define HD     1024
#define NHEAD  16
#define DHEAD  64
#define N3     3072          // 3*Hd
#define M_ROWS 8192          // B*S

typedef __bf16 bf16_t;
typedef __bf16 bf16x4 __attribute__((ext_vector_type(4)));
typedef __bf16 bf16x8 __attribute__((ext_vector_type(8)));
typedef float  floatx4 __attribute__((ext_vector_type(4)));

__device__ __forceinline__ float bf2f(bf16_t x) { return (float)x; }
__device__ __forceinline__ bf16_t f2bf(float f) { return (bf16_t)f; }  // RNE fptrunc
__device__ __forceinline__ float fexp2(float x) { return __builtin_amdgcn_exp2f(x); }

#define QKSCALE 0.1803368801111204f   // 0.125 * log2(e), folded into K in k1

__device__ __forceinline__ bf16x8 cvt8(const float4 lo, const float4 hi) {
    bf16x8 r;
    r[0] = (bf16_t)lo.x; r[1] = (bf16_t)lo.y; r[2] = (bf16_t)lo.z; r[3] = (bf16_t)lo.w;
    r[4] = (bf16_t)hi.x; r[5] = (bf16_t)hi.y; r[6] = (bf16_t)hi.z; r[7] = (bf16_t)hi.w;
    return r;
}

// ---------------------------------------------------------------------------
// Kernel 1 (round-3 structure, ~165 us): qkv = X @ W^T + b, fused RoPE on
// q,k; K pre-scaled by 0.125*log2(e) so attn softmax runs in base-2 with no
// scale mul. Scatter bf16 [b][h][s][d]. [d][s] scatter banned (round 4).
// ---------------------------------------------------------------------------
__global__ __launch_bounds__(256, 3)
void qkv_rope_kernel(const float* __restrict__ X, const float* __restrict__ W,
                     const float* __restrict__ bias,
                     bf16_t* __restrict__ qws, bf16_t* __restrict__ kws,
                     bf16_t* __restrict__ vws)
{
    __shared__ bf16_t As[128 * 32];   // 8 KB, [row][32] bf16 (16-dword rows)
    __shared__ bf16_t Bs[128 * 32];   // 8 KB

    const int tid  = threadIdx.x;
    const int wave = tid >> 6;
    const int lane = tid & 63;
    const int l15  = lane & 15;
    const int quad = lane >> 4;
    const int wm   = wave >> 1;
    const int wn   = wave & 1;
    const int m0   = blockIdx.y * 128;
    const int n0   = blockIdx.x * 128;

    const int b0   = tid;
    const int b1   = tid + 256;
    const int r0   = b0 >> 2, c0 = (b0 & 3) * 8;
    const int r1   = b1 >> 2, c1 = (b1 & 3) * 8;

    const float* gA0 = X + (size_t)(m0 + r0) * HD + c0;
    const float* gA1 = X + (size_t)(m0 + r1) * HD + c1;
    const float* gB0 = W + (size_t)(n0 + r0) * HD + c0;
    const float* gB1 = W + (size_t)(n0 + r1) * HD + c1;

    floatx4 acc[4][4];
#pragma unroll
    for (int i = 0; i < 4; ++i)
#pragma unroll
        for (int j = 0; j < 4; ++j)
            acc[i][j] = (floatx4){0.f, 0.f, 0.f, 0.f};

    float4 a0l = *(const float4*)(gA0);     float4 a0h = *(const float4*)(gA0 + 4);
    float4 a1l = *(const float4*)(gA1);     float4 a1h = *(const float4*)(gA1 + 4);
    float4 w0l = *(const float4*)(gB0);     float4 w0h = *(const float4*)(gB0 + 4);
    float4 w1l = *(const float4*)(gB1);     float4 w1h = *(const float4*)(gB1 + 4);

    for (int kt = 0; kt < 32; ++kt) {
        *(bf16x8*)(As + r0 * 32 + c0) = cvt8(a0l, a0h);
        *(bf16x8*)(As + r1 * 32 + c1) = cvt8(a1l, a1h);
        *(bf16x8*)(Bs + r0 * 32 + c0) = cvt8(w0l, w0h);
        *(bf16x8*)(Bs + r1 * 32 + c1) = cvt8(w1l, w1h);
        __syncthreads();

        if (kt + 1 < 32) {
            const int k0 = (kt + 1) * 32;
            a0l = *(const float4*)(gA0 + k0);  a0h = *(const float4*)(gA0 + k0 + 4);
            a1l = *(const float4*)(gA1 + k0);  a1h = *(const float4*)(gA1 + k0 + 4);
            w0l = *(const float4*)(gB0 + k0);  w0h = *(const float4*)(gB0 + k0 + 4);
            w1l = *(const float4*)(gB1 + k0);  w1h = *(const float4*)(gB1 + k0 + 4);
        }

        bf16x8 af[4], bfr[4];
#pragma unroll
        for (int t = 0; t < 4; ++t) {
            af[t]  = *(const bf16x8*)(As + (wm * 64 + t * 16 + l15) * 32 + quad * 8);
            bfr[t] = *(const bf16x8*)(Bs + (wn * 64 + t * 16 + l15) * 32 + quad * 8);
        }
#pragma unroll
        for (int i = 0; i < 4; ++i)
#pragma unroll
            for (int j = 0; j < 4; ++j)
                acc[i][j] = __builtin_amdgcn_mfma_f32_16x16x32_bf16(
                    af[i], bfr[j], acc[i][j], 0, 0, 0);
        __syncthreads();
    }

    // Epilogue: bias + RoPE + scatter. C/D: col=lane&15, row=quad*4+reg.
#pragma unroll
    for (int i = 0; i < 4; ++i) {
        const int mrow_base = m0 + wm * 64 + i * 16 + quad * 4;
#pragma unroll
        for (int j = 0; j < 2; ++j) {
            const int n1 = n0 + wn * 64 + j * 16 + l15;    // dim in [0,32)
            const int n2 = n1 + 32;
            const float b1 = bias[n1];
            const float b2 = bias[n2];
            const int which = n1 >> 10;          // 0=q 1=k 2=v (wave-uniform)
            const int hd    = n1 & 1023;
            const int head  = hd >> 6;
            const int dim   = hd & 63;           // < 32 by construction
            const float inv_freq = expf(-(float)dim * 0.28782313662425572f);
            bf16_t* outp = (which == 0) ? qws : (which == 1) ? kws : vws;
#pragma unroll
            for (int r = 0; r < 4; ++r) {
                const int mrow = mrow_base + r;
                const int s    = mrow & (S_LEN - 1);
                const int bb   = mrow >> 11;
                float x1 = acc[i][j][r]     + b1;
                float x2 = acc[i][j + 2][r] + b2;
                float o1, o2;
                if (which < 2) {
                    const float ang = (float)s * inv_freq;
                    float cs = cosf(ang);
                    float sn = sinf(ang);
                    if (which == 1) { cs *= QKSCALE; sn *= QKSCALE; }
                    o1 = x1 * cs - x2 * sn;
                    o2 = x2 * cs + x1 * sn;
                } else {
                    o1 = x1; o2 = x2;
                }
                const size_t off = ((size_t)(bb * NHEAD + head) * S_LEN + s) * DHEAD + dim;
                outp[off]      = f2bf(o1);
                outp[off + 32] = f2bf(o2);
            }
        }
    }
}

// ---------------------------------------------------------------------------
// Kernel 2: flash attention, operand-swapped QK^T (S^T = K Q^T): lane owns
// one q-row -> softmax = local max/sum + xor16/xor32 shuffles only. P written
// t-contiguous b64 into [q][t] stride-72 wave-private slab, read b128. V
// transposed in-LDS to rotate-swizzled [d][t] stride-64 (conflict-free).
// K pre-scaled in k1 -> base-2 softmax, no muls. grid=(bh,qt) XCD locality.
// __launch_bounds__(256,3): round 8's (256,4) forced a 64-VGPR budget ->
// per-iteration scratch spill (WRITE_SIZE 294 MB). 3 waves/EU = 170 cap.
// ---------------------------------------------------------------------------
#define STK 72
#define STP 72

__global__ __launch_bounds__(256, 3)
void attn_kernel(const bf16_t* __restrict__ qws, const bf16_t* __restrict__ kws,
                 const bf16_t* __restrict__ vws, float* __restrict__ out)
{
    __shared__ bf16_t Ks[64 * STK];    // 9216 B  K [t][d]
    __shared__ bf16_t Vt[64 * 64];     // 8192 B  V^T [d][t], rotate-swizzled
    __shared__ bf16_t Ps[128 * STP];   // 18432 B P [q][t], wave-private rows

    const int tid  = threadIdx.x;
    const int wave = tid >> 6;
    const int lane = tid & 63;
    const int l15  = lane & 15;
    const int quad = lane >> 4;
    const int bh   = blockIdx.x;          // 0..63  (XCD = bh % 8)
    const int qt   = blockIdx.y;          // 0..15
    const size_t baseS = (size_t)bh * S_LEN * DHEAD;
    const int q0 = qt * 128 + wave * 32;

    // Q fragments (B-operand: n=q on lane&15, k=d on quad*8+j), persistent.
    bf16x8 aq[2][2];
#pragma unroll
    for (int qsub = 0; qsub < 2; ++qsub)
#pragma unroll
        for (int kb = 0; kb < 2; ++kb)
            aq[qsub][kb] = *(const bf16x8*)(qws + baseS +
                (size_t)(q0 + qsub * 16 + l15) * DHEAD + kb * 32 + quad * 8);

    // staging coords: 64 t-rows x 64 d-cols, 2 x uint4 per thread per matrix
    const int srow = tid >> 2;            // t
    const int scol = (tid & 3) * 8;       // d base

    uint4 kreg[2], vreg[2];
#pragma unroll
    for (int jj = 0; jj < 2; ++jj) {
        kreg[jj] = *(const uint4*)(kws + baseS + (size_t)srow * DHEAD + scol + jj * 32);
        vreg[jj] = *(const uint4*)(vws + baseS + (size_t)srow * DHEAD + scol + jj * 32);
    }

    float m_i[2] = {-1e30f, -1e30f};      // per-lane state for q = qsub*16+l15
    float l_i[2] = {0.f, 0.f};            // (replicated across quads)
    floatx4 o_acc[2][4];
#pragma unroll
    for (int qsub = 0; qsub < 2; ++qsub)
#pragma unroll
        for (int dt = 0; dt < 4; ++dt)
            o_acc[qsub][dt] = (floatx4){0.f, 0.f, 0.f, 0.f};

    for (int kt = 0; kt < 32; ++kt) {
        // --- stage K row-major; V transposed with rotate swizzle -----------
#pragma unroll
        for (int jj = 0; jj < 2; ++jj) {
            *(uint4*)(Ks + srow * STK + scol + jj * 32) = kreg[jj];
            bf16_t vv[8];
            *(uint4*)vv = vreg[jj];
            const int dbase = scol + jj * 32;
#pragma unroll
            for (int e = 0; e < 8; ++e) {
                const int d = dbase + e;
                const int trot = (srow + 16 * ((d >> 3) & 3)) & 63;
                Vt[d * 64 + trot] = vv[e];
            }
        }
        __syncthreads();

        // prefetch next tile
        if (kt + 1 < 32) {
            const int t0 = (kt + 1) * 64;
#pragma unroll
            for (int jj = 0; jj < 2; ++jj) {
                kreg[jj] = *(const uint4*)(kws + baseS + (size_t)(t0 + srow) * DHEAD + scol + jj * 32);
                vreg[jj] = *(const uint4*)(vws + baseS + (size_t)(t0 + srow) * DHEAD + scol + jj * 32);
            }
        }

        // --- S^T = K Q^T : C row = t (quad*4+r), col = q (l15) -------------
        floatx4 st[2][4];
#pragma unroll
        for (int qsub = 0; qsub < 2; ++qsub)
#pragma unroll
            for (int mt = 0; mt < 4; ++mt)
                st[qsub][mt] = (floatx4){0.f, 0.f, 0.f, 0.f};
#pragma unroll
        for (int kb = 0; kb < 2; ++kb)
#pragma unroll
            for (int mt = 0; mt < 4; ++mt) {
                bf16x8 ak = *(const bf16x8*)(Ks + (mt * 16 + l15) * STK + kb * 32 + quad * 8);
#pragma unroll
                for (int qsub = 0; qsub < 2; ++qsub)
                    st[qsub][mt] = __builtin_amdgcn_mfma_f32_16x16x32_bf16(
                        ak, aq[qsub][kb], st[qsub][mt], 0, 0, 0);
            }

        // --- online softmax: lane owns q = qsub*16+l15, 16 t-values local --
        float alphaL[2];
#pragma unroll
        for (int qsub = 0; qsub < 2; ++qsub) {
            float mx = st[qsub][0][0];
#pragma unroll
            for (int mt = 0; mt < 4; ++mt)
#pragma unroll
                for (int r = 0; r < 4; ++r)
                    mx = fmaxf(mx, st[qsub][mt][r]);
            mx = fmaxf(mx, __shfl_xor(mx, 16, 64));
            mx = fmaxf(mx, __shfl_xor(mx, 32, 64));
            const float mnew = fmaxf(m_i[qsub], mx);
            alphaL[qsub] = fexp2(m_i[qsub] - mnew);
            float rs = 0.f;
#pragma unroll
            for (int mt = 0; mt < 4; ++mt) {
                bf16x4 pb;
#pragma unroll
                for (int r = 0; r < 4; ++r) {
                    const float p = fexp2(st[qsub][mt][r] - mnew);
                    pb[r] = f2bf(p);
                    rs += bf2f(pb[r]);
                }
                *(bf16x4*)(Ps + (wave * 32 + qsub * 16 + l15) * STP + mt * 16 + quad * 4) = pb;
            }
            rs += __shfl_xor(rs, 16, 64);
            rs += __shfl_xor(rs, 32, 64);
            l_i[qsub] = l_i[qsub] * alphaL[qsub] + rs;
            m_i[qsub] = mnew;
        }

        // --- rescale O (alpha moved to C-layout rows via one shfl per r) ---
#pragma unroll
        for (int qsub = 0; qsub < 2; ++qsub)
#pragma unroll
            for (int r = 0; r < 4; ++r) {
                const float a = __shfl(alphaL[qsub], (lane & 48) | (quad * 4 + r), 64);
#pragma unroll
                for (int dt = 0; dt < 4; ++dt)
                    o_acc[qsub][dt][r] *= a;
            }

        // --- O += P V : A = P [q][t] (b128), B = V^T [d][t] (b128) ---------
#pragma unroll
        for (int kb = 0; kb < 2; ++kb) {
            bf16x8 bv[4];
#pragma unroll
            for (int dt = 0; dt < 4; ++dt) {
                const int d = dt * 16 + l15;
                const int trot = (kb * 32 + quad * 8 + 16 * ((d >> 3) & 3)) & 63;
                bv[dt] = *(const bf16x8*)(Vt + d * 64 + trot);
            }
#pragma unroll
            for (int qsub = 0; qsub < 2; ++qsub) {
                bf16x8 ap = *(const bf16x8*)(Ps + (wave * 32 + qsub * 16 + l15) * STP + kb * 32 + quad * 8);
#pragma unroll
                for (int dt = 0; dt < 4; ++dt)
                    o_acc[qsub][dt] = __builtin_amdgcn_mfma_f32_16x16x32_bf16(
                        ap, bv[dt], o_acc[qsub][dt], 0, 0, 0);
            }
        }
        __syncthreads();
    }

    // normalize + store out[b][s][h*64+d] (fp32); l transposed via shfl
    const int bb = bh >> 4, hh = bh & 15;
#pragma unroll
    for (int qsub = 0; qsub < 2; ++qsub)
#pragma unroll
        for (int r = 0; r < 4; ++r) {
            const float lv  = __shfl(l_i[qsub], (lane & 48) | (quad * 4 + r), 64);
            const float inv = 1.0f / lv;
            const int s = q0 + qsub * 16 + quad * 4 + r;
            const size_t off0 = ((size_t)(bb * S_LEN + s)) * HD + hh * DHEAD;
#pragma unroll
            for (int dt = 0; dt < 4; ++dt)
                out[off0 + dt * 16 + l15] = o_acc[qsub][dt][r] * inv;
        }
}

extern "C" void kernel_launch(void* const* d_in, const int* in_sizes, int n_in,
                              void* d_out, int out_size, void* d_ws, size_t ws_size,
                              hipStream_t stream) {
    const float* X    = (const float*)d_in[0];   // (4,2048,1024) fp32
    const float* W    = (const float*)d_in[1];   // (3072,1024) fp32
    const float* bias = (const float*)d_in[2];   // (3072,) fp32
    float* out = (float*)d_out;                  // (4,2048,1024) fp32

    const size_t per = (size_t)B_SZ * NHEAD * S_LEN * DHEAD;   // 8.39M elems
    bf16_t* qws = (bf16_t*)d_ws;
    bf16_t* kws = qws + per;
    bf16_t* vws = kws + per;

    qkv_rope_kernel<<<dim3(N3 / 128, M_ROWS / 128), 256, 0, stream>>>(
        X, W, bias, qws, kws, vws);
    attn_kernel<<<dim3(B_SZ * NHEAD, S_LEN / 128), 256, 0, stream>>>(
        qws, kws, vws, out);
}